// Round 15
// baseline (433.788 us; speedup 1.0000x reference)
//
#include <hip/hip_runtime.h>
#include <math.h>

// Problem constants (fixed by setup_inputs):
// B=2, W=12, N=10000, F=16, HID=32, H=2, M=B*N=20000
// E0 total = 320000 edges; +M self loops => E_TOT = 340000
// Only t=10 and t=11 feed the final output (conv tail, last position).
#define M_NODES 20000
#define N_PER_B 10000
#define E0T     320000
#define E_TOT   340000

// ---------------- CSR build ----------------

__global__ void hist_kernel(const int* __restrict__ eidx, int* __restrict__ cnt) {
    int e = blockIdx.x * blockDim.x + threadIdx.x;
    if (e >= E_TOT) return;
    int d = (e < E0T) ? eidx[E0T + e] : (e - E0T);
    atomicAdd(&cnt[d], 1);
}

__global__ void scan_kernel(const int* __restrict__ cnt, int* __restrict__ offsets,
                            int* __restrict__ cursor) {
    __shared__ int sdata[1024];
    const int CHUNK = 20; // 1024*20 = 20480 >= 20000
    int tid = threadIdx.x;
    int begin = tid * CHUNK;
    int end = begin + CHUNK; if (end > M_NODES) end = M_NODES;
    if (begin > M_NODES) begin = M_NODES;
    int s = 0;
    for (int i = begin; i < end; ++i) s += cnt[i];
    sdata[tid] = s;
    __syncthreads();
    for (int off = 1; off < 1024; off <<= 1) {
        int v = (tid >= off) ? sdata[tid - off] : 0;
        __syncthreads();
        sdata[tid] += v;
        __syncthreads();
    }
    int run = (tid == 0) ? 0 : sdata[tid - 1];
    for (int i = begin; i < end; ++i) {
        offsets[i] = run; cursor[i] = run; run += cnt[i];
    }
    if (tid == 1023) offsets[M_NODES] = sdata[1023];
}

__global__ void scatter_kernel(const int* __restrict__ eidx, int* __restrict__ cursor,
                               int* __restrict__ ssrc) {
    int e = blockIdx.x * blockDim.x + threadIdx.x;
    if (e >= E_TOT) return;
    int s, d;
    if (e < E0T) { s = eidx[e]; d = eidx[E0T + e]; }
    else         { s = e - E0T; d = s; }
    int pos = atomicAdd(&cursor[d], 1);
    ssrc[pos] = s;
}

// Deterministic CSR: sort each dst bucket by src.
// One WAVE per bucket, bitonic sort across 64 lanes (avg deg 17, max ~40).
// Serial fallback on lane 0 if a bucket somehow exceeds 64.
__global__ void sort_kernel(const int* __restrict__ offsets, int* __restrict__ ssrc) {
    int w = (blockIdx.x * blockDim.x + threadIdx.x) >> 6;
    int lane = threadIdx.x & 63;
    if (w >= M_NODES) return;
    int s = offsets[w], e = offsets[w + 1];
    int len = e - s;
    if (len <= 1) return;
    if (len <= 64) {
        int v = (lane < len) ? ssrc[s + lane] : 0x7fffffff;
        #pragma unroll
        for (int k = 2; k <= 64; k <<= 1) {
            #pragma unroll
            for (int j = k >> 1; j > 0; j >>= 1) {
                int partner = __shfl_xor(v, j, 64);
                bool ascending = ((lane & k) == 0);
                bool lower = ((lane & j) == 0);
                bool keepMin = (lower == ascending);
                v = keepMin ? min(v, partner) : max(v, partner);
            }
        }
        if (lane < len) ssrc[s + lane] = v;
    } else if (lane == 0) {
        for (int i = s + 1; i < e; ++i) {
            int v = ssrc[i]; int j = i - 1;
            while (j >= s && ssrc[j] > v) { ssrc[j + 1] = ssrc[j]; --j; }
            ssrc[j + 1] = v;
        }
    }
}

// ---------------- layer-1 projection + logits ----------------
// wave per node; lane = output channel c in [0,64); head = lane>>5.
// Writes h1 row + per-head attention logits (shfl-reduce within each 32-lane head).
__global__ void proj1_kernel(const float* __restrict__ x, const float* __restrict__ W1,
                             const float* __restrict__ as1, const float* __restrict__ ad1,
                             float* __restrict__ h1, float* __restrict__ asv,
                             float* __restrict__ adv, int tt) {
    int w = (blockIdx.x * blockDim.x + threadIdx.x) >> 6;
    int lane = threadIdx.x & 63;
    if (w >= M_NODES) return;
    int b = w / N_PER_B, n = w - b * N_PER_B;
    const float* xr = x + ((size_t)((b * 12 + 10 + tt) * N_PER_B + n)) * 16;
    float acc = 0.f;
    #pragma unroll
    for (int f = 0; f < 16; ++f) acc += xr[f] * W1[f * 64 + lane];
    h1[(size_t)w * 64 + lane] = acc;
    float sv = acc * as1[lane];   // as1 flat (H,C) == lane
    float dv = acc * ad1[lane];
    #pragma unroll
    for (int off = 16; off >= 1; off >>= 1) {
        sv += __shfl_xor(sv, off, 64);
        dv += __shfl_xor(dv, off, 64);
    }
    if ((lane & 31) == 0) {
        asv[w * 2 + (lane >> 5)] = sv;
        adv[w * 2 + (lane >> 5)] = dv;
    }
}

// ---------------- layer-1 softmax-aggregate (gathers precomputed h1) ----------------
__global__ void agg1_kernel(const int* __restrict__ offsets, const int* __restrict__ ssrc,
                            const float* __restrict__ h1, const float* __restrict__ asv,
                            const float* __restrict__ adv, const float* __restrict__ b1,
                            float* __restrict__ out1) {
    int w = (blockIdx.x * blockDim.x + threadIdx.x) >> 6;
    int lane = threadIdx.x & 63;
    if (w >= M_NODES) return;
    int m = w;
    int head = lane >> 5, k = lane & 31;
    int start = offsets[m], end = offsets[m + 1];
    float ad = adv[m * 2 + head];
    float mx = -1e30f;
    for (int e = start + k; e < end; e += 32) {
        float v = asv[ssrc[e] * 2 + head] + ad;
        v = v > 0.f ? v : 0.2f * v;
        mx = fmaxf(mx, v);
    }
    #pragma unroll
    for (int off = 16; off >= 1; off >>= 1) mx = fmaxf(mx, __shfl_xor(mx, off, 64));
    float sm = 0.f;
    for (int e = start + k; e < end; e += 32) {
        float v = asv[ssrc[e] * 2 + head] + ad;
        v = v > 0.f ? v : 0.2f * v;
        sm += expf(v - mx);
    }
    #pragma unroll
    for (int off = 16; off >= 1; off >>= 1) sm += __shfl_xor(sm, off, 64);
    float inv = 1.f / sm;
    float acc = 0.f;
    for (int e = start; e < end; ++e) {
        int s = ssrc[e];
        float v = asv[s * 2 + head] + ad;
        v = v > 0.f ? v : 0.2f * v;
        acc += expf(v - mx) * inv * h1[(size_t)s * 64 + lane];
    }
    float r = acc + b1[lane];
    out1[(size_t)m * 64 + lane] = r > 0.f ? r : 0.f;
}

// ---------------- layer-2 projection + logits ----------------
__global__ void proj2_kernel(const float* __restrict__ out1, const float* __restrict__ W2,
                             const float* __restrict__ as2, const float* __restrict__ ad2,
                             float* __restrict__ h2p, float* __restrict__ asv, float* __restrict__ adv) {
    int w = (blockIdx.x * blockDim.x + threadIdx.x) >> 6;
    int lane = threadIdx.x & 63;
    if (w >= M_NODES) return;
    float xv = out1[(size_t)w * 64 + lane];
    float acc = 0.f;
    #pragma unroll
    for (int f = 0; f < 64; ++f) acc += __shfl(xv, f, 64) * W2[f * 64 + lane];
    h2p[(size_t)w * 64 + lane] = acc;
    float sv = acc * as2[lane];
    float dv = acc * ad2[lane];
    #pragma unroll
    for (int off = 16; off >= 1; off >>= 1) {
        sv += __shfl_xor(sv, off, 64);
        dv += __shfl_xor(dv, off, 64);
    }
    if ((lane & 31) == 0) {
        asv[w * 2 + (lane >> 5)] = sv;
        adv[w * 2 + (lane >> 5)] = dv;
    }
}

// ---------------- layer-2 softmax-aggregate (mean heads) ----------------
__global__ void agg2_kernel(const int* __restrict__ offsets, const int* __restrict__ ssrc,
                            const float* __restrict__ h2p, const float* __restrict__ asv,
                            const float* __restrict__ adv, const float* __restrict__ b2,
                            float* __restrict__ h2, int tt) {
    int w = (blockIdx.x * blockDim.x + threadIdx.x) >> 6;
    int lane = threadIdx.x & 63;
    if (w >= M_NODES) return;
    int m = w;
    int head = lane >> 5, k = lane & 31;
    int start = offsets[m], end = offsets[m + 1];
    float ad = adv[m * 2 + head];
    float mx = -1e30f;
    for (int e = start + k; e < end; e += 32) {
        float v = asv[ssrc[e] * 2 + head] + ad;
        v = v > 0.f ? v : 0.2f * v;
        mx = fmaxf(mx, v);
    }
    #pragma unroll
    for (int off = 16; off >= 1; off >>= 1) mx = fmaxf(mx, __shfl_xor(mx, off, 64));
    float sm = 0.f;
    for (int e = start + k; e < end; e += 32) {
        float v = asv[ssrc[e] * 2 + head] + ad;
        v = v > 0.f ? v : 0.2f * v;
        sm += expf(v - mx);
    }
    #pragma unroll
    for (int off = 16; off >= 1; off >>= 1) sm += __shfl_xor(sm, off, 64);
    float inv = 1.f / sm;
    float acc = 0.f;
    for (int e = start; e < end; ++e) {
        int s = ssrc[e];
        float v = asv[s * 2 + head] + ad;
        v = v > 0.f ? v : 0.2f * v;
        acc += expf(v - mx) * inv * h2p[(size_t)s * 64 + lane];
    }
    float other = __shfl_xor(acc, 32, 64);
    if (lane < 32) {
        float r = 0.5f * (acc + other) + b2[lane];
        h2[((size_t)tt * M_NODES + m) * 32 + lane] = r > 0.f ? r : 0.f;
    }
}

// ---------------- fused conv tail (last position) + FC ----------------
// 2 nodes per wave; within each 32-lane half, lane = output channel co.
// 64 independent FMAs per lane, then ONE 5-stage 32-lane reduce (vs 32 reduces before).
__global__ void final_kernel(const float* __restrict__ h2, const float* __restrict__ wconv,
                             const float* __restrict__ bconv, const float* __restrict__ wfc,
                             const float* __restrict__ bfc, float* __restrict__ out) {
    int w = (blockIdx.x * blockDim.x + threadIdx.x) >> 6;
    int lane = threadIdx.x & 63;
    int half = lane >> 5, co = lane & 31;
    int m = w * 2 + half;
    if (m >= M_NODES) return;
    const float* r10 = h2 + ((size_t)0 * M_NODES + m) * 32;  // t=10 row
    const float* r11 = h2 + ((size_t)1 * M_NODES + m) * 32;  // t=11 row
    float t = bconv[co];
    #pragma unroll
    for (int i = 0; i < 32; ++i) {
        t += r10[i] * wconv[(co * 32 + i) * 3 + 0];
        t += r11[i] * wconv[(co * 32 + i) * 3 + 1];
    }
    t = t > 0.f ? t : 0.f;
    float p = t * wfc[co];
    #pragma unroll
    for (int off = 16; off >= 1; off >>= 1) p += __shfl_xor(p, off, 64); // within-half reduce
    if (co == 0) out[m] = p + bfc[0];
}

extern "C" void kernel_launch(void* const* d_in, const int* in_sizes, int n_in,
                              void* d_out, int out_size, void* d_ws, size_t ws_size,
                              hipStream_t stream) {
    const float* x     = (const float*)d_in[0];
    const int*   eidx  = (const int*)d_in[1];
    const float* W1    = (const float*)d_in[2];
    const float* as1   = (const float*)d_in[3];
    const float* ad1   = (const float*)d_in[4];
    const float* b1    = (const float*)d_in[5];
    const float* W2    = (const float*)d_in[6];
    const float* as2   = (const float*)d_in[7];
    const float* ad2   = (const float*)d_in[8];
    const float* b2    = (const float*)d_in[9];
    const float* wconv = (const float*)d_in[10];
    const float* bconv = (const float*)d_in[11];
    const float* wfc   = (const float*)d_in[12];
    const float* bfc   = (const float*)d_in[13];
    float* out = (float*)d_out;

    // Workspace layout — total ~17.3 MB (kept well under ws_size).
    // hbuf is aliased: h1 during proj1->agg1, h2p during proj2->agg2 (disjoint live ranges).
    char* ws = (char*)d_ws;
    auto alloc = [&](size_t bytes) -> char* {
        char* p = ws;
        ws += (bytes + 255) & ~(size_t)255;
        return p;
    };
    int*   cnt     = (int*)alloc((M_NODES + 1) * sizeof(int));     // 80 KB
    int*   offsets = (int*)alloc((M_NODES + 1) * sizeof(int));     // 80 KB
    int*   cursor  = (int*)alloc((M_NODES + 1) * sizeof(int));     // 80 KB
    int*   ssrc    = (int*)alloc((size_t)E_TOT * sizeof(int));     // 1.36 MB
    float* asv     = (float*)alloc((size_t)M_NODES * 2 * sizeof(float)); // 160 KB
    float* adv     = (float*)alloc((size_t)M_NODES * 2 * sizeof(float)); // 160 KB
    float* out1    = (float*)alloc((size_t)M_NODES * 64 * sizeof(float)); // 5.12 MB (per-t)
    float* hbuf    = (float*)alloc((size_t)M_NODES * 64 * sizeof(float)); // 5.12 MB (h1 / h2p)
    float* h2      = (float*)alloc((size_t)2 * M_NODES * 32 * sizeof(float)); // 5.12 MB (both t)

    hipMemsetAsync(cnt, 0, (M_NODES + 1) * sizeof(int), stream);

    int ethreads = 256, eblocks = (E_TOT + ethreads - 1) / ethreads;
    hist_kernel<<<eblocks, ethreads, 0, stream>>>(eidx, cnt);
    scan_kernel<<<1, 1024, 0, stream>>>(cnt, offsets, cursor);
    scatter_kernel<<<eblocks, ethreads, 0, stream>>>(eidx, cursor, ssrc);
    // one wave per bucket: 20000 waves -> 5000 blocks of 256
    sort_kernel<<<(M_NODES * 64) / 256, 256, 0, stream>>>(offsets, ssrc);

    int blocks_m = (M_NODES * 64) / 256;      // 5000 blocks, 1 wave per node

    for (int tt = 0; tt < 2; ++tt) {
        proj1_kernel<<<blocks_m, 256, 0, stream>>>(x, W1, as1, ad1, hbuf, asv, adv, tt);
        agg1_kernel<<<blocks_m, 256, 0, stream>>>(offsets, ssrc, hbuf, asv, adv, b1, out1);
        proj2_kernel<<<blocks_m, 256, 0, stream>>>(out1, W2, as2, ad2, hbuf, asv, adv);
        agg2_kernel<<<blocks_m, 256, 0, stream>>>(offsets, ssrc, hbuf, asv, adv, b2, h2, tt);
    }

    // 2 nodes per wave -> 10000 waves -> 2500 blocks
    final_kernel<<<(M_NODES / 2 * 64) / 256, 256, 0, stream>>>(h2, wconv, bconv, wfc, bfc, out);
}

// Round 16
// 352.727 us; speedup vs baseline: 1.2298x; 1.2298x over previous
//
#include <hip/hip_runtime.h>
#include <math.h>

// Problem constants (fixed by setup_inputs):
// B=2, W=12, N=10000, F=16, HID=32, H=2, M=B*N=20000
// E0 total = 320000 edges; +M self loops => E_TOT = 340000
// Only t=10 and t=11 feed the final output (conv tail, last position).
#define M_NODES 20000
#define N_PER_B 10000
#define E0T     320000
#define E_TOT   340000

// ---------------- CSR build ----------------

__global__ void hist_kernel(const int* __restrict__ eidx, int* __restrict__ cnt) {
    int e = blockIdx.x * blockDim.x + threadIdx.x;
    if (e >= E_TOT) return;
    int d = (e < E0T) ? eidx[E0T + e] : (e - E0T);
    atomicAdd(&cnt[d], 1);
}

__global__ void scan_kernel(const int* __restrict__ cnt, int* __restrict__ offsets,
                            int* __restrict__ cursor) {
    __shared__ int sdata[1024];
    const int CHUNK = 20; // 1024*20 = 20480 >= 20000
    int tid = threadIdx.x;
    int begin = tid * CHUNK;
    int end = begin + CHUNK; if (end > M_NODES) end = M_NODES;
    if (begin > M_NODES) begin = M_NODES;
    int s = 0;
    for (int i = begin; i < end; ++i) s += cnt[i];
    sdata[tid] = s;
    __syncthreads();
    for (int off = 1; off < 1024; off <<= 1) {
        int v = (tid >= off) ? sdata[tid - off] : 0;
        __syncthreads();
        sdata[tid] += v;
        __syncthreads();
    }
    int run = (tid == 0) ? 0 : sdata[tid - 1];
    for (int i = begin; i < end; ++i) {
        offsets[i] = run; cursor[i] = run; run += cnt[i];
    }
    if (tid == 1023) offsets[M_NODES] = sdata[1023];
}

__global__ void scatter_kernel(const int* __restrict__ eidx, int* __restrict__ cursor,
                               int* __restrict__ ssrc) {
    int e = blockIdx.x * blockDim.x + threadIdx.x;
    if (e >= E_TOT) return;
    int s, d;
    if (e < E0T) { s = eidx[e]; d = eidx[E0T + e]; }
    else         { s = e - E0T; d = s; }
    int pos = atomicAdd(&cursor[d], 1);
    ssrc[pos] = s;
}

// Deterministic CSR: sort each dst bucket by src.
// One WAVE per bucket, bitonic sort across 64 lanes (avg deg 17, max ~40).
// Serial fallback on lane 0 if a bucket somehow exceeds 64.
__global__ void sort_kernel(const int* __restrict__ offsets, int* __restrict__ ssrc) {
    int w = (blockIdx.x * blockDim.x + threadIdx.x) >> 6;
    int lane = threadIdx.x & 63;
    if (w >= M_NODES) return;
    int s = offsets[w], e = offsets[w + 1];
    int len = e - s;
    if (len <= 1) return;
    if (len <= 64) {
        int v = (lane < len) ? ssrc[s + lane] : 0x7fffffff;
        #pragma unroll
        for (int k = 2; k <= 64; k <<= 1) {
            #pragma unroll
            for (int j = k >> 1; j > 0; j >>= 1) {
                int partner = __shfl_xor(v, j, 64);
                bool ascending = ((lane & k) == 0);
                bool lower = ((lane & j) == 0);
                bool keepMin = (lower == ascending);
                v = keepMin ? min(v, partner) : max(v, partner);
            }
        }
        if (lane < len) ssrc[s + lane] = v;
    } else if (lane == 0) {
        for (int i = s + 1; i < e; ++i) {
            int v = ssrc[i]; int j = i - 1;
            while (j >= s && ssrc[j] > v) { ssrc[j + 1] = ssrc[j]; --j; }
            ssrc[j + 1] = v;
        }
    }
}

// ---------------- layer-1 projection + logits ----------------
__global__ void proj1_kernel(const float* __restrict__ x, const float* __restrict__ W1,
                             const float* __restrict__ as1, const float* __restrict__ ad1,
                             float* __restrict__ h1, float* __restrict__ asv,
                             float* __restrict__ adv, int tt) {
    int w = (blockIdx.x * blockDim.x + threadIdx.x) >> 6;
    int lane = threadIdx.x & 63;
    if (w >= M_NODES) return;
    int b = w / N_PER_B, n = w - b * N_PER_B;
    const float* xr = x + ((size_t)((b * 12 + 10 + tt) * N_PER_B + n)) * 16;
    float acc = 0.f;
    #pragma unroll
    for (int f = 0; f < 16; ++f) acc += xr[f] * W1[f * 64 + lane];
    h1[(size_t)w * 64 + lane] = acc;
    float sv = acc * as1[lane];   // as1 flat (H,C) == lane
    float dv = acc * ad1[lane];
    #pragma unroll
    for (int off = 16; off >= 1; off >>= 1) {
        sv += __shfl_xor(sv, off, 64);
        dv += __shfl_xor(dv, off, 64);
    }
    if ((lane & 31) == 0) {
        asv[w * 2 + (lane >> 5)] = sv;
        adv[w * 2 + (lane >> 5)] = dv;
    }
}

// ---------------- layer-1 softmax-aggregate (LDS-staged exp weights) ----------------
__global__ void agg1_kernel(const int* __restrict__ offsets, const int* __restrict__ ssrc,
                            const float* __restrict__ h1, const float* __restrict__ asv,
                            const float* __restrict__ adv, const float* __restrict__ b1,
                            float* __restrict__ out1) {
    __shared__ float swgt[4][64][2]; // [wave in block][edge][head], wave-private
    int w = (blockIdx.x * blockDim.x + threadIdx.x) >> 6;
    int wv = threadIdx.x >> 6;
    int lane = threadIdx.x & 63;
    if (w >= M_NODES) return;
    int m = w;
    int head = lane >> 5, k = lane & 31;
    int start = offsets[m], end = offsets[m + 1];
    int len = end - start;
    float ad = adv[m * 2 + head];
    float mx = -1e30f;
    for (int e = start + k; e < end; e += 32) {
        float v = asv[ssrc[e] * 2 + head] + ad;
        v = v > 0.f ? v : 0.2f * v;
        mx = fmaxf(mx, v);
    }
    #pragma unroll
    for (int off = 16; off >= 1; off >>= 1) mx = fmaxf(mx, __shfl_xor(mx, off, 64));
    float sm = 0.f;
    if (len <= 64) {
        for (int e = start + k; e < end; e += 32) {
            float v = asv[ssrc[e] * 2 + head] + ad;
            v = v > 0.f ? v : 0.2f * v;
            float ex = expf(v - mx);
            swgt[wv][e - start][head] = ex;
            sm += ex;
        }
        #pragma unroll
        for (int off = 16; off >= 1; off >>= 1) sm += __shfl_xor(sm, off, 64);
        float inv = 1.f / sm;
        float acc = 0.f;
        for (int j = 0; j < len; ++j) {
            int s = ssrc[start + j];
            acc += swgt[wv][j][head] * h1[(size_t)s * 64 + lane];
        }
        float r = acc * inv + b1[lane];
        out1[(size_t)m * 64 + lane] = r > 0.f ? r : 0.f;
    } else {
        // fallback (buckets >64 never expected)
        for (int e = start + k; e < end; e += 32) {
            float v = asv[ssrc[e] * 2 + head] + ad;
            v = v > 0.f ? v : 0.2f * v;
            sm += expf(v - mx);
        }
        #pragma unroll
        for (int off = 16; off >= 1; off >>= 1) sm += __shfl_xor(sm, off, 64);
        float inv = 1.f / sm;
        float acc = 0.f;
        for (int e = start; e < end; ++e) {
            int s = ssrc[e];
            float v = asv[s * 2 + head] + ad;
            v = v > 0.f ? v : 0.2f * v;
            acc += expf(v - mx) * inv * h1[(size_t)s * 64 + lane];
        }
        float r = acc + b1[lane];
        out1[(size_t)m * 64 + lane] = r > 0.f ? r : 0.f;
    }
}

// ---------------- layer-2 projection + logits ----------------
__global__ void proj2_kernel(const float* __restrict__ out1, const float* __restrict__ W2,
                             const float* __restrict__ as2, const float* __restrict__ ad2,
                             float* __restrict__ h2p, float* __restrict__ asv, float* __restrict__ adv) {
    int w = (blockIdx.x * blockDim.x + threadIdx.x) >> 6;
    int lane = threadIdx.x & 63;
    if (w >= M_NODES) return;
    float xv = out1[(size_t)w * 64 + lane];
    float acc = 0.f;
    #pragma unroll
    for (int f = 0; f < 64; ++f) acc += __shfl(xv, f, 64) * W2[f * 64 + lane];
    h2p[(size_t)w * 64 + lane] = acc;
    float sv = acc * as2[lane];
    float dv = acc * ad2[lane];
    #pragma unroll
    for (int off = 16; off >= 1; off >>= 1) {
        sv += __shfl_xor(sv, off, 64);
        dv += __shfl_xor(dv, off, 64);
    }
    if ((lane & 31) == 0) {
        asv[w * 2 + (lane >> 5)] = sv;
        adv[w * 2 + (lane >> 5)] = dv;
    }
}

// ---------------- layer-2 softmax-aggregate (LDS-staged exp weights, mean heads) ----------------
__global__ void agg2_kernel(const int* __restrict__ offsets, const int* __restrict__ ssrc,
                            const float* __restrict__ h2p, const float* __restrict__ asv,
                            const float* __restrict__ adv, const float* __restrict__ b2,
                            float* __restrict__ h2, int tt) {
    __shared__ float swgt[4][64][2];
    int w = (blockIdx.x * blockDim.x + threadIdx.x) >> 6;
    int wv = threadIdx.x >> 6;
    int lane = threadIdx.x & 63;
    if (w >= M_NODES) return;
    int m = w;
    int head = lane >> 5, k = lane & 31;
    int start = offsets[m], end = offsets[m + 1];
    int len = end - start;
    float ad = adv[m * 2 + head];
    float mx = -1e30f;
    for (int e = start + k; e < end; e += 32) {
        float v = asv[ssrc[e] * 2 + head] + ad;
        v = v > 0.f ? v : 0.2f * v;
        mx = fmaxf(mx, v);
    }
    #pragma unroll
    for (int off = 16; off >= 1; off >>= 1) mx = fmaxf(mx, __shfl_xor(mx, off, 64));
    float sm = 0.f;
    float accn;
    if (len <= 64) {
        for (int e = start + k; e < end; e += 32) {
            float v = asv[ssrc[e] * 2 + head] + ad;
            v = v > 0.f ? v : 0.2f * v;
            float ex = expf(v - mx);
            swgt[wv][e - start][head] = ex;
            sm += ex;
        }
        #pragma unroll
        for (int off = 16; off >= 1; off >>= 1) sm += __shfl_xor(sm, off, 64);
        float inv = 1.f / sm;
        float acc = 0.f;
        for (int j = 0; j < len; ++j) {
            int s = ssrc[start + j];
            acc += swgt[wv][j][head] * h2p[(size_t)s * 64 + lane];
        }
        accn = acc * inv;
    } else {
        for (int e = start + k; e < end; e += 32) {
            float v = asv[ssrc[e] * 2 + head] + ad;
            v = v > 0.f ? v : 0.2f * v;
            sm += expf(v - mx);
        }
        #pragma unroll
        for (int off = 16; off >= 1; off >>= 1) sm += __shfl_xor(sm, off, 64);
        float inv = 1.f / sm;
        float acc = 0.f;
        for (int e = start; e < end; ++e) {
            int s = ssrc[e];
            float v = asv[s * 2 + head] + ad;
            v = v > 0.f ? v : 0.2f * v;
            acc += expf(v - mx) * inv * h2p[(size_t)s * 64 + lane];
        }
        accn = acc;
    }
    float other = __shfl_xor(accn, 32, 64);
    if (lane < 32) {
        float r = 0.5f * (accn + other) + b2[lane];
        h2[((size_t)tt * M_NODES + m) * 32 + lane] = r > 0.f ? r : 0.f;
    }
}

// ---------------- fused conv tail (last position) + FC ----------------
// 2 nodes per wave; within each 32-lane half, lane = output channel co.
__global__ void final_kernel(const float* __restrict__ h2, const float* __restrict__ wconv,
                             const float* __restrict__ bconv, const float* __restrict__ wfc,
                             const float* __restrict__ bfc, float* __restrict__ out) {
    int w = (blockIdx.x * blockDim.x + threadIdx.x) >> 6;
    int lane = threadIdx.x & 63;
    int half = lane >> 5, co = lane & 31;
    int m = w * 2 + half;
    if (m >= M_NODES) return;
    const float* r10 = h2 + ((size_t)0 * M_NODES + m) * 32;  // t=10 row
    const float* r11 = h2 + ((size_t)1 * M_NODES + m) * 32;  // t=11 row
    float t = bconv[co];
    #pragma unroll
    for (int i = 0; i < 32; ++i) {
        t += r10[i] * wconv[(co * 32 + i) * 3 + 0];
        t += r11[i] * wconv[(co * 32 + i) * 3 + 1];
    }
    t = t > 0.f ? t : 0.f;
    float p = t * wfc[co];
    #pragma unroll
    for (int off = 16; off >= 1; off >>= 1) p += __shfl_xor(p, off, 64); // within-half reduce
    if (co == 0) out[m] = p + bfc[0];
}

extern "C" void kernel_launch(void* const* d_in, const int* in_sizes, int n_in,
                              void* d_out, int out_size, void* d_ws, size_t ws_size,
                              hipStream_t stream) {
    const float* x     = (const float*)d_in[0];
    const int*   eidx  = (const int*)d_in[1];
    const float* W1    = (const float*)d_in[2];
    const float* as1   = (const float*)d_in[3];
    const float* ad1   = (const float*)d_in[4];
    const float* b1    = (const float*)d_in[5];
    const float* W2    = (const float*)d_in[6];
    const float* as2   = (const float*)d_in[7];
    const float* ad2   = (const float*)d_in[8];
    const float* b2    = (const float*)d_in[9];
    const float* wconv = (const float*)d_in[10];
    const float* bconv = (const float*)d_in[11];
    const float* wfc   = (const float*)d_in[12];
    const float* bfc   = (const float*)d_in[13];
    float* out = (float*)d_out;

    // Workspace layout — total ~17.3 MB (kept well under ws_size).
    // hbuf is aliased: h1 during proj1->agg1, h2p during proj2->agg2 (disjoint live ranges).
    char* ws = (char*)d_ws;
    auto alloc = [&](size_t bytes) -> char* {
        char* p = ws;
        ws += (bytes + 255) & ~(size_t)255;
        return p;
    };
    int*   cnt     = (int*)alloc((M_NODES + 1) * sizeof(int));     // 80 KB
    int*   offsets = (int*)alloc((M_NODES + 1) * sizeof(int));     // 80 KB
    int*   cursor  = (int*)alloc((M_NODES + 1) * sizeof(int));     // 80 KB
    int*   ssrc    = (int*)alloc((size_t)E_TOT * sizeof(int));     // 1.36 MB
    float* asv     = (float*)alloc((size_t)M_NODES * 2 * sizeof(float)); // 160 KB
    float* adv     = (float*)alloc((size_t)M_NODES * 2 * sizeof(float)); // 160 KB
    float* out1    = (float*)alloc((size_t)M_NODES * 64 * sizeof(float)); // 5.12 MB (per-t)
    float* hbuf    = (float*)alloc((size_t)M_NODES * 64 * sizeof(float)); // 5.12 MB (h1 / h2p)
    float* h2      = (float*)alloc((size_t)2 * M_NODES * 32 * sizeof(float)); // 5.12 MB (both t)

    hipMemsetAsync(cnt, 0, (M_NODES + 1) * sizeof(int), stream);

    int ethreads = 256, eblocks = (E_TOT + ethreads - 1) / ethreads;
    hist_kernel<<<eblocks, ethreads, 0, stream>>>(eidx, cnt);
    scan_kernel<<<1, 1024, 0, stream>>>(cnt, offsets, cursor);
    scatter_kernel<<<eblocks, ethreads, 0, stream>>>(eidx, cursor, ssrc);
    // one wave per bucket: 20000 waves -> 5000 blocks of 256
    sort_kernel<<<(M_NODES * 64) / 256, 256, 0, stream>>>(offsets, ssrc);

    int blocks_m = (M_NODES * 64) / 256;      // 5000 blocks, 1 wave per node

    for (int tt = 0; tt < 2; ++tt) {
        proj1_kernel<<<blocks_m, 256, 0, stream>>>(x, W1, as1, ad1, hbuf, asv, adv, tt);
        agg1_kernel<<<blocks_m, 256, 0, stream>>>(offsets, ssrc, hbuf, asv, adv, b1, out1);
        proj2_kernel<<<blocks_m, 256, 0, stream>>>(out1, W2, as2, ad2, hbuf, asv, adv);
        agg2_kernel<<<blocks_m, 256, 0, stream>>>(offsets, ssrc, hbuf, asv, adv, b2, h2, tt);
    }

    // 2 nodes per wave -> 10000 waves -> 2500 blocks
    final_kernel<<<(M_NODES / 2 * 64) / 256, 256, 0, stream>>>(h2, wconv, bconv, wfc, bfc, out);
}

// Round 20
// 330.363 us; speedup vs baseline: 1.3131x; 1.0677x over previous
//
#include <hip/hip_runtime.h>
#include <math.h>

// Problem constants (fixed by setup_inputs):
// B=2, W=12, N=10000, F=16, HID=32, H=2, M=B*N=20000
// E0 total = 320000 edges; +M self loops => E_TOT = 340000
// Only t=10 and t=11 feed the final output (conv tail, last position).
// Both t-passes fused into single launches: wave index w in [0, 2*M), tt = w / M.
#define M_NODES 20000
#define N_PER_B 10000
#define E0T     320000
#define E_TOT   340000

// ---------------- CSR build ----------------

__global__ void hist_kernel(const int* __restrict__ eidx, int* __restrict__ cnt) {
    int e = blockIdx.x * blockDim.x + threadIdx.x;
    if (e >= E_TOT) return;
    int d = (e < E0T) ? eidx[E0T + e] : (e - E0T);
    atomicAdd(&cnt[d], 1);
}

__global__ void scan_kernel(const int* __restrict__ cnt, int* __restrict__ offsets,
                            int* __restrict__ cursor) {
    __shared__ int sdata[1024];
    const int CHUNK = 20; // 1024*20 = 20480 >= 20000
    int tid = threadIdx.x;
    int begin = tid * CHUNK;
    int end = begin + CHUNK; if (end > M_NODES) end = M_NODES;
    if (begin > M_NODES) begin = M_NODES;
    int s = 0;
    for (int i = begin; i < end; ++i) s += cnt[i];
    sdata[tid] = s;
    __syncthreads();
    for (int off = 1; off < 1024; off <<= 1) {
        int v = (tid >= off) ? sdata[tid - off] : 0;
        __syncthreads();
        sdata[tid] += v;
        __syncthreads();
    }
    int run = (tid == 0) ? 0 : sdata[tid - 1];
    for (int i = begin; i < end; ++i) {
        offsets[i] = run; cursor[i] = run; run += cnt[i];
    }
    if (tid == 1023) offsets[M_NODES] = sdata[1023];
}

__global__ void scatter_kernel(const int* __restrict__ eidx, int* __restrict__ cursor,
                               int* __restrict__ ssrc) {
    int e = blockIdx.x * blockDim.x + threadIdx.x;
    if (e >= E_TOT) return;
    int s, d;
    if (e < E0T) { s = eidx[e]; d = eidx[E0T + e]; }
    else         { s = e - E0T; d = s; }
    int pos = atomicAdd(&cursor[d], 1);
    ssrc[pos] = s;
}

// Deterministic CSR: sort each dst bucket by src.
// One WAVE per bucket, bitonic sort across 64 lanes (avg deg 17, max ~40).
__global__ void sort_kernel(const int* __restrict__ offsets, int* __restrict__ ssrc) {
    int w = (blockIdx.x * blockDim.x + threadIdx.x) >> 6;
    int lane = threadIdx.x & 63;
    if (w >= M_NODES) return;
    int s = offsets[w], e = offsets[w + 1];
    int len = e - s;
    if (len <= 1) return;
    if (len <= 64) {
        int v = (lane < len) ? ssrc[s + lane] : 0x7fffffff;
        #pragma unroll
        for (int k = 2; k <= 64; k <<= 1) {
            #pragma unroll
            for (int j = k >> 1; j > 0; j >>= 1) {
                int partner = __shfl_xor(v, j, 64);
                bool ascending = ((lane & k) == 0);
                bool lower = ((lane & j) == 0);
                bool keepMin = (lower == ascending);
                v = keepMin ? min(v, partner) : max(v, partner);
            }
        }
        if (lane < len) ssrc[s + lane] = v;
    } else if (lane == 0) {
        for (int i = s + 1; i < e; ++i) {
            int v = ssrc[i]; int j = i - 1;
            while (j >= s && ssrc[j] > v) { ssrc[j + 1] = ssrc[j]; --j; }
            ssrc[j + 1] = v;
        }
    }
}

// ---------------- layer-1 projection + logits (both t-passes) ----------------
// wave per (tt,node); lane = output channel c in [0,64); head = lane>>5.
__global__ void proj1_kernel(const float* __restrict__ x, const float* __restrict__ W1,
                             const float* __restrict__ as1, const float* __restrict__ ad1,
                             float* __restrict__ h1, float* __restrict__ asv,
                             float* __restrict__ adv) {
    int w = (blockIdx.x * blockDim.x + threadIdx.x) >> 6;
    int lane = threadIdx.x & 63;
    if (w >= 2 * M_NODES) return;
    int tt = w / M_NODES;
    int m = w - tt * M_NODES;
    int b = m / N_PER_B, n = m - b * N_PER_B;
    const float* xr = x + ((size_t)((b * 12 + 10 + tt) * N_PER_B + n)) * 16;
    float acc = 0.f;
    #pragma unroll
    for (int f = 0; f < 16; ++f) acc += xr[f] * W1[f * 64 + lane];
    h1[(size_t)w * 64 + lane] = acc;
    float sv = acc * as1[lane];   // as1 flat (H,C) == lane
    float dv = acc * ad1[lane];
    #pragma unroll
    for (int off = 16; off >= 1; off >>= 1) {
        sv += __shfl_xor(sv, off, 64);
        dv += __shfl_xor(dv, off, 64);
    }
    if ((lane & 31) == 0) {
        asv[w * 2 + (lane >> 5)] = sv;
        adv[w * 2 + (lane >> 5)] = dv;
    }
}

// ---------------- layer-1 softmax-aggregate (LDS-staged exp weights, both t) ----------------
__global__ void agg1_kernel(const int* __restrict__ offsets, const int* __restrict__ ssrc,
                            const float* __restrict__ h1, const float* __restrict__ asv,
                            const float* __restrict__ adv, const float* __restrict__ b1,
                            float* __restrict__ out1) {
    __shared__ float swgt[4][64][2]; // [wave in block][edge][head], wave-private
    int w = (blockIdx.x * blockDim.x + threadIdx.x) >> 6;
    int wv = threadIdx.x >> 6;
    int lane = threadIdx.x & 63;
    if (w >= 2 * M_NODES) return;
    int tt = w / M_NODES;
    int m = w - tt * M_NODES;
    size_t tb = (size_t)tt * M_NODES;
    int head = lane >> 5, k = lane & 31;
    int start = offsets[m], end = offsets[m + 1];
    int len = end - start;
    float ad = adv[w * 2 + head];
    float mx = -1e30f;
    for (int e = start + k; e < end; e += 32) {
        float v = asv[(tb + ssrc[e]) * 2 + head] + ad;
        v = v > 0.f ? v : 0.2f * v;
        mx = fmaxf(mx, v);
    }
    #pragma unroll
    for (int off = 16; off >= 1; off >>= 1) mx = fmaxf(mx, __shfl_xor(mx, off, 64));
    float sm = 0.f;
    if (len <= 64) {
        for (int e = start + k; e < end; e += 32) {
            float v = asv[(tb + ssrc[e]) * 2 + head] + ad;
            v = v > 0.f ? v : 0.2f * v;
            float ex = expf(v - mx);
            swgt[wv][e - start][head] = ex;
            sm += ex;
        }
        #pragma unroll
        for (int off = 16; off >= 1; off >>= 1) sm += __shfl_xor(sm, off, 64);
        float inv = 1.f / sm;
        float acc = 0.f;
        for (int j = 0; j < len; ++j) {
            int s = ssrc[start + j];
            acc += swgt[wv][j][head] * h1[(tb + s) * 64 + lane];
        }
        float r = acc * inv + b1[lane];
        out1[(size_t)w * 64 + lane] = r > 0.f ? r : 0.f;
    } else {
        for (int e = start + k; e < end; e += 32) {
            float v = asv[(tb + ssrc[e]) * 2 + head] + ad;
            v = v > 0.f ? v : 0.2f * v;
            sm += expf(v - mx);
        }
        #pragma unroll
        for (int off = 16; off >= 1; off >>= 1) sm += __shfl_xor(sm, off, 64);
        float inv = 1.f / sm;
        float acc = 0.f;
        for (int e = start; e < end; ++e) {
            int s = ssrc[e];
            float v = asv[(tb + s) * 2 + head] + ad;
            v = v > 0.f ? v : 0.2f * v;
            acc += expf(v - mx) * inv * h1[(tb + s) * 64 + lane];
        }
        float r = acc + b1[lane];
        out1[(size_t)w * 64 + lane] = r > 0.f ? r : 0.f;
    }
}

// ---------------- layer-2 projection + logits (both t) ----------------
__global__ void proj2_kernel(const float* __restrict__ out1, const float* __restrict__ W2,
                             const float* __restrict__ as2, const float* __restrict__ ad2,
                             float* __restrict__ h2p, float* __restrict__ asv, float* __restrict__ adv) {
    int w = (blockIdx.x * blockDim.x + threadIdx.x) >> 6;
    int lane = threadIdx.x & 63;
    if (w >= 2 * M_NODES) return;
    float xv = out1[(size_t)w * 64 + lane];
    float acc = 0.f;
    #pragma unroll
    for (int f = 0; f < 64; ++f) acc += __shfl(xv, f, 64) * W2[f * 64 + lane];
    h2p[(size_t)w * 64 + lane] = acc;
    float sv = acc * as2[lane];
    float dv = acc * ad2[lane];
    #pragma unroll
    for (int off = 16; off >= 1; off >>= 1) {
        sv += __shfl_xor(sv, off, 64);
        dv += __shfl_xor(dv, off, 64);
    }
    if ((lane & 31) == 0) {
        asv[w * 2 + (lane >> 5)] = sv;
        adv[w * 2 + (lane >> 5)] = dv;
    }
}

// ---------------- layer-2 softmax-aggregate (LDS-staged, mean heads, both t) ----------------
__global__ void agg2_kernel(const int* __restrict__ offsets, const int* __restrict__ ssrc,
                            const float* __restrict__ h2p, const float* __restrict__ asv,
                            const float* __restrict__ adv, const float* __restrict__ b2,
                            float* __restrict__ h2) {
    __shared__ float swgt[4][64][2];
    int w = (blockIdx.x * blockDim.x + threadIdx.x) >> 6;
    int wv = threadIdx.x >> 6;
    int lane = threadIdx.x & 63;
    if (w >= 2 * M_NODES) return;
    int tt = w / M_NODES;
    int m = w - tt * M_NODES;
    size_t tb = (size_t)tt * M_NODES;
    int head = lane >> 5, k = lane & 31;
    int start = offsets[m], end = offsets[m + 1];
    int len = end - start;
    float ad = adv[w * 2 + head];
    float mx = -1e30f;
    for (int e = start + k; e < end; e += 32) {
        float v = asv[(tb + ssrc[e]) * 2 + head] + ad;
        v = v > 0.f ? v : 0.2f * v;
        mx = fmaxf(mx, v);
    }
    #pragma unroll
    for (int off = 16; off >= 1; off >>= 1) mx = fmaxf(mx, __shfl_xor(mx, off, 64));
    float sm = 0.f;
    float accn;
    if (len <= 64) {
        for (int e = start + k; e < end; e += 32) {
            float v = asv[(tb + ssrc[e]) * 2 + head] + ad;
            v = v > 0.f ? v : 0.2f * v;
            float ex = expf(v - mx);
            swgt[wv][e - start][head] = ex;
            sm += ex;
        }
        #pragma unroll
        for (int off = 16; off >= 1; off >>= 1) sm += __shfl_xor(sm, off, 64);
        float inv = 1.f / sm;
        float acc = 0.f;
        for (int j = 0; j < len; ++j) {
            int s = ssrc[start + j];
            acc += swgt[wv][j][head] * h2p[(tb + s) * 64 + lane];
        }
        accn = acc * inv;
    } else {
        for (int e = start + k; e < end; e += 32) {
            float v = asv[(tb + ssrc[e]) * 2 + head] + ad;
            v = v > 0.f ? v : 0.2f * v;
            sm += expf(v - mx);
        }
        #pragma unroll
        for (int off = 16; off >= 1; off >>= 1) sm += __shfl_xor(sm, off, 64);
        float inv = 1.f / sm;
        float acc = 0.f;
        for (int e = start; e < end; ++e) {
            int s = ssrc[e];
            float v = asv[(tb + s) * 2 + head] + ad;
            v = v > 0.f ? v : 0.2f * v;
            acc += expf(v - mx) * inv * h2p[(tb + s) * 64 + lane];
        }
        accn = acc;
    }
    float other = __shfl_xor(accn, 32, 64);
    if (lane < 32) {
        float r = 0.5f * (accn + other) + b2[lane];
        h2[(size_t)w * 32 + lane] = r > 0.f ? r : 0.f;  // w = tt*M + m matches [tt][M][32]
    }
}

// ---------------- fused conv tail (last position) + FC ----------------
// 2 nodes per wave; within each 32-lane half, lane = output channel co.
__global__ void final_kernel(const float* __restrict__ h2, const float* __restrict__ wconv,
                             const float* __restrict__ bconv, const float* __restrict__ wfc,
                             const float* __restrict__ bfc, float* __restrict__ out) {
    int w = (blockIdx.x * blockDim.x + threadIdx.x) >> 6;
    int lane = threadIdx.x & 63;
    int half = lane >> 5, co = lane & 31;
    int m = w * 2 + half;
    if (m >= M_NODES) return;
    const float* r10 = h2 + ((size_t)0 * M_NODES + m) * 32;  // t=10 row
    const float* r11 = h2 + ((size_t)1 * M_NODES + m) * 32;  // t=11 row
    float t = bconv[co];
    #pragma unroll
    for (int i = 0; i < 32; ++i) {
        t += r10[i] * wconv[(co * 32 + i) * 3 + 0];
        t += r11[i] * wconv[(co * 32 + i) * 3 + 1];
    }
    t = t > 0.f ? t : 0.f;
    float p = t * wfc[co];
    #pragma unroll
    for (int off = 16; off >= 1; off >>= 1) p += __shfl_xor(p, off, 64); // within-half reduce
    if (co == 0) out[m] = p + bfc[0];
}

extern "C" void kernel_launch(void* const* d_in, const int* in_sizes, int n_in,
                              void* d_out, int out_size, void* d_ws, size_t ws_size,
                              hipStream_t stream) {
    const float* x     = (const float*)d_in[0];
    const int*   eidx  = (const int*)d_in[1];
    const float* W1    = (const float*)d_in[2];
    const float* as1   = (const float*)d_in[3];
    const float* ad1   = (const float*)d_in[4];
    const float* b1    = (const float*)d_in[5];
    const float* W2    = (const float*)d_in[6];
    const float* as2   = (const float*)d_in[7];
    const float* ad2   = (const float*)d_in[8];
    const float* b2    = (const float*)d_in[9];
    const float* wconv = (const float*)d_in[10];
    const float* bconv = (const float*)d_in[11];
    const float* wfc   = (const float*)d_in[12];
    const float* bfc   = (const float*)d_in[13];
    float* out = (float*)d_out;

    // Workspace layout — ~28 MB total (ws_size = 256 MB, plenty).
    // hbuf aliased: h1 during proj1->agg1, h2p during proj2->agg2 (disjoint live ranges).
    char* ws = (char*)d_ws;
    auto alloc = [&](size_t bytes) -> char* {
        char* p = ws;
        ws += (bytes + 255) & ~(size_t)255;
        return p;
    };
    int*   cnt     = (int*)alloc((M_NODES + 1) * sizeof(int));
    int*   offsets = (int*)alloc((M_NODES + 1) * sizeof(int));
    int*   cursor  = (int*)alloc((M_NODES + 1) * sizeof(int));
    int*   ssrc    = (int*)alloc((size_t)E_TOT * sizeof(int));
    float* asv     = (float*)alloc((size_t)2 * M_NODES * 2 * sizeof(float)); // 320 KB
    float* adv     = (float*)alloc((size_t)2 * M_NODES * 2 * sizeof(float)); // 320 KB
    float* out1    = (float*)alloc((size_t)2 * M_NODES * 64 * sizeof(float)); // 10.24 MB
    float* hbuf    = (float*)alloc((size_t)2 * M_NODES * 64 * sizeof(float)); // 10.24 MB (h1 / h2p)
    float* h2      = (float*)alloc((size_t)2 * M_NODES * 32 * sizeof(float)); // 5.12 MB

    hipMemsetAsync(cnt, 0, (M_NODES + 1) * sizeof(int), stream);

    int ethreads = 256, eblocks = (E_TOT + ethreads - 1) / ethreads;
    hist_kernel<<<eblocks, ethreads, 0, stream>>>(eidx, cnt);
    scan_kernel<<<1, 1024, 0, stream>>>(cnt, offsets, cursor);
    scatter_kernel<<<eblocks, ethreads, 0, stream>>>(eidx, cursor, ssrc);
    sort_kernel<<<(M_NODES * 64) / 256, 256, 0, stream>>>(offsets, ssrc);

    int blocks_2m = (2 * M_NODES * 64) / 256;  // 10000 blocks, 1 wave per (tt,node)

    proj1_kernel<<<blocks_2m, 256, 0, stream>>>(x, W1, as1, ad1, hbuf, asv, adv);
    agg1_kernel<<<blocks_2m, 256, 0, stream>>>(offsets, ssrc, hbuf, asv, adv, b1, out1);
    proj2_kernel<<<blocks_2m, 256, 0, stream>>>(out1, W2, as2, ad2, hbuf, asv, adv);
    agg2_kernel<<<blocks_2m, 256, 0, stream>>>(offsets, ssrc, hbuf, asv, adv, b2, h2);

    // 2 nodes per wave -> 10000 waves -> 2500 blocks
    final_kernel<<<(M_NODES / 2 * 64) / 256, 256, 0, stream>>>(h2, wconv, bconv, wfc, bfc, out);
}